// Round 7
// baseline (467.733 us; speedup 1.0000x reference)
//
#include <hip/hip_runtime.h>
#include <math.h>

#define NUM_NODES 94
#define NP 96
#define SEQ_LEN 784
#define OUT_CLASSES 10
#define E_BLK 2          // elements per block
#define TPE 96           // threads per element: 12 row-groups x 8 k-chunks
#define THREADS (E_BLK * TPE)   // 192

#define TWO_GAMMA 0.2f
#define OM2 0.0503551324598949f            // (2*pi/28)^2
#define INV_SQRT_N 0.103142124625879       // 1/sqrt(94)
#define LOG2E 1.4426950408889634
// A = I*INV_SQRT_N ; exp2 arg = 2A*log2e -> fold 2*INV_SQRT_N*LOG2E into weights
#define WSCALE ((float)(2.0 * INV_SQRT_N * LOG2E))

typedef float f2 __attribute__((ext_vector_type(2)));
typedef float f4 __attribute__((ext_vector_type(4)));

__device__ __forceinline__ float dpp_xor1(float x) {   // quad_perm(1,0,3,2)
    return __int_as_float(__builtin_amdgcn_mov_dpp(__float_as_int(x), 0xB1, 0xF, 0xF, true));
}
__device__ __forceinline__ float dpp_xor2(float x) {   // quad_perm(2,3,0,1)
    return __int_as_float(__builtin_amdgcn_mov_dpp(__float_as_int(x), 0x4E, 0xF, 0xF, true));
}
__device__ __forceinline__ float dpp_mir8(float x) {   // ROW_HALF_MIRROR: i <-> 7-i in 8
    return __int_as_float(__builtin_amdgcn_mov_dpp(__float_as_int(x), 0x141, 0xF, 0xF, true));
}

// r=8 rows x k=12 cols per thread (W = 96 floats). LDS y-broadcast cost is
// 432/r cyc per element-step on the CU-shared LDS pipe — r=8 is the whole
// point of this design (R1-R6 all had r<=2 -> ~1000 LDS cyc/CU-step plateau).
__global__
__attribute__((amdgpu_waves_per_eu(2, 4)))
__launch_bounds__(THREADS)
void horn_kernel(
    const float* __restrict__ input,   // (1024, 784)
    const float* __restrict__ w_ih,    // (94, 1)
    const float* __restrict__ b_ih,    // (94)
    const float* __restrict__ w_hh,    // (94, 94)
    const float* __restrict__ b_hh,    // (94)
    const float* __restrict__ w_ro,    // (10, 94)
    const float* __restrict__ b_ro,    // (10)
    float* __restrict__ out)           // (1024, 10)
{
    __shared__ __align__(16) float ylds[2][E_BLK][NP];     // double-buffered y
    __shared__ __align__(16) float slds[E_BLK][SEQ_LEN];   // input rows

    const int tid  = threadIdx.x;
    const int elem = tid / TPE;          // 0..1
    const int rem  = tid - elem * TPE;   // 0..95
    const int q    = rem >> 3;           // row-group 0..11 -> rows 8q..8q+7
    const int kq   = rem & 7;            // k-chunk 0..7 -> cols 12kq..12kq+11
    const int b0e  = blockIdx.x * E_BLK;

    // Prefetch input rows (contiguous, float4-coalesced).
    {
        const f4* in4 = (const f4*)(input + (size_t)b0e * SEQ_LEN);
        f4* s4 = (f4*)&slds[0][0];
        #pragma unroll 1
        for (int i = tid; i < E_BLK * SEQ_LEN / 4; i += THREADS) s4[i] = in4[i];
    }
    // Zero y buffers: 2*2*96 = 384 floats over 192 threads.
    ((float*)ylds)[tid] = 0.0f;
    ((float*)ylds)[tid + THREADS] = 0.0f;

    // W block: rows 8q..8q+7, cols 12kq..12kq+11, pre-scaled by WSCALE.
    // VOLATILE loads: cannot be re-executed/rematerialized, so the values
    // must stay resident (VGPR best case, AGPR-copy worst case — never the
    // per-step L1 re-fetch that flatlined R2-R6).
    const int row0 = 8 * q, col0 = 12 * kq;
    f2 w2[8][6];
    {
        const volatile float* wv = w_hh;
        #pragma unroll
        for (int i = 0; i < 8; i++) {
            const int rr = row0 + i;
            #pragma unroll
            for (int c = 0; c < 12; c++) {
                const int cc = col0 + c;
                float v = 0.0f;
                if (rr < NUM_NODES && cc < NUM_NODES)
                    v = wv[rr * NUM_NODES + cc] * WSCALE;
                w2[i][c >> 1][c & 1] = v;
            }
        }
    }

    // Butterfly transpose-reduce select bits (see stage verification in notes):
    // c0=b0^b2, c1=b1^b2, c2=b2 -> lane kq owns row 4*b2 + 2*(b1^b2) + (b0^b2).
    const int  b0 = kq & 1, b1 = (kq >> 1) & 1, b2 = kq >> 2;
    const bool c0 = (b0 ^ b2) != 0;
    const bool c1 = (b1 ^ b2) != 0;
    const bool c2 = b2 != 0;
    const int  nown = row0 + 4 * b2 + 2 * (b1 ^ b2) + (b0 ^ b2);
    const bool act  = (nown < NUM_NODES);
    const float wih  = act ? w_ih[nown] * WSCALE : 0.0f;
    const float bias = act ? (b_ih[nown] + b_hh[nown]) * WSCALE : 0.0f;

    float x = 0.0f, y = 0.0f;

    const f4* ybase0 = (const f4*)&ylds[0][elem][col0];   // 48B*kq: 16B-aligned
    const f4* ybase1 = (const f4*)&ylds[1][elem][col0];

    __syncthreads();

    #define STEP(PB, YB, TIDX)                                                \
    {                                                                         \
        f2 p0={0,0},p1={0,0},p2={0,0},p3={0,0},p4={0,0},p5={0,0},p6={0,0},p7={0,0}; \
        _Pragma("unroll")                                                     \
        for (int jj = 0; jj < 3; jj++) {                                      \
            f4 Y = (YB)[jj];                                                  \
            f2 lo = __builtin_shufflevector(Y, Y, 0, 1);                      \
            f2 hi = __builtin_shufflevector(Y, Y, 2, 3);                      \
            p0 += w2[0][2*jj] * lo;  p0 += w2[0][2*jj+1] * hi;                \
            p1 += w2[1][2*jj] * lo;  p1 += w2[1][2*jj+1] * hi;                \
            p2 += w2[2][2*jj] * lo;  p2 += w2[2][2*jj+1] * hi;                \
            p3 += w2[3][2*jj] * lo;  p3 += w2[3][2*jj+1] * hi;                \
            p4 += w2[4][2*jj] * lo;  p4 += w2[4][2*jj+1] * hi;                \
            p5 += w2[5][2*jj] * lo;  p5 += w2[5][2*jj+1] * hi;                \
            p6 += w2[6][2*jj] * lo;  p6 += w2[6][2*jj+1] * hi;                \
            p7 += w2[7][2*jj] * lo;  p7 += w2[7][2*jj+1] * hi;                \
        }                                                                     \
        float P0 = p0[0]+p0[1], P1 = p1[0]+p1[1], P2 = p2[0]+p2[1];           \
        float P3 = p3[0]+p3[1], P4 = p4[0]+p4[1], P5 = p5[0]+p5[1];           \
        float P6 = p6[0]+p6[1], P7 = p7[0]+p7[1];                             \
        /* stage 1 (xor1): pairs (0,1)(2,3)(4,5)(6,7) */                      \
        float Q0 = (c0 ? P1 : P0) + dpp_xor1(c0 ? P0 : P1);                   \
        float Q1 = (c0 ? P3 : P2) + dpp_xor1(c0 ? P2 : P3);                   \
        float Q2 = (c0 ? P5 : P4) + dpp_xor1(c0 ? P4 : P5);                   \
        float Q3 = (c0 ? P7 : P6) + dpp_xor1(c0 ? P6 : P7);                   \
        /* stage 2 (xor2) */                                                  \
        float R0 = (c1 ? Q1 : Q0) + dpp_xor2(c1 ? Q0 : Q1);                   \
        float R1 = (c1 ? Q3 : Q2) + dpp_xor2(c1 ? Q2 : Q3);                   \
        /* stage 3 (mirror within 8) */                                       \
        float S  = (c2 ? R1 : R0) + dpp_mir8(c2 ? R0 : R1);                   \
        float st   = slds[elem][TIDX];                                        \
        float earg = fmaf(st, wih, bias) + S;        /* = 2A*log2e */         \
        float e    = __builtin_amdgcn_exp2f(earg);                            \
        float accel = 0.5f - __builtin_amdgcn_rcpf(e + 1.0f); /* 0.5*tanh */  \
        accel = fmaf(-TWO_GAMMA, y, accel);                                   \
        accel = fmaf(-OM2, x, accel);                                         \
        x += y;                                      /* H = 1 */              \
        y += accel;                                                           \
        ylds[PB ^ 1][elem][nown] = y;                                         \
        __syncthreads();                                                      \
    }

    for (int t = 0; t < SEQ_LEN; t += 2) {
        STEP(0, ybase0, t)
        STEP(1, ybase1, t + 1)
    }
    #undef STEP

    // Stash x (buffers dead after final barrier), then project.
    ylds[0][elem][nown] = x;
    __syncthreads();

    if (tid < E_BLK * OUT_CLASSES * 4) {       // 80 threads, quad-aligned
        const int e  = tid / 40;
        const int rm = tid % 40;
        const int c  = rm >> 2;
        const int k2 = rm & 3;
        float s = 0.0f;
        #pragma unroll
        for (int i = 0; i < 24; i++) {
            const int j = k2 * 24 + i;
            if (j < NUM_NODES) s += ylds[0][e][j] * w_ro[c * NUM_NODES + j];
        }
        s += dpp_xor1(s);
        s += dpp_xor2(s);
        if (k2 == 0) out[(size_t)(b0e + e) * OUT_CLASSES + c] = s + b_ro[c];
    }
}

extern "C" void kernel_launch(void* const* d_in, const int* in_sizes, int n_in,
                              void* d_out, int out_size, void* d_ws, size_t ws_size,
                              hipStream_t stream) {
    const float* input = (const float*)d_in[0];
    const float* w_ih  = (const float*)d_in[1];
    const float* b_ih  = (const float*)d_in[2];
    const float* w_hh  = (const float*)d_in[3];
    const float* b_hh  = (const float*)d_in[4];
    const float* w_ro  = (const float*)d_in[5];
    const float* b_ro  = (const float*)d_in[6];
    float* out = (float*)d_out;

    const int batch = in_sizes[0] / SEQ_LEN;   // 1024
    dim3 grid(batch / E_BLK);                  // 512 blocks -> 2 per CU
    dim3 block(THREADS);                       // 192 threads = 3 waves

    hipLaunchKernelGGL(horn_kernel, grid, block, 0, stream,
                       input, w_ih, b_ih, w_hh, b_hh, w_ro, b_ro, out);
}

// Round 8
// 378.608 us; speedup vs baseline: 1.2354x; 1.2354x over previous
//
#include <hip/hip_runtime.h>
#include <math.h>

#define NUM_NODES 94
#define SEQ_LEN 784
#define OUT_CLASSES 10

#define TWO_GAMMA 0.2f
#define OM2 0.0503551324598949f            // (2*pi/28)^2
#define INV_SQRT_N 0.103142124625879       // 1/sqrt(94)
#define LOG2E 1.4426950408889634
// exp2 arg = 2A*log2e -> fold 2*INV_SQRT_N*LOG2E into all I-path weights
#define WSCALE ((float)(2.0 * INV_SQRT_N * LOG2E))

typedef float f2 __attribute__((ext_vector_type(2)));

__device__ __forceinline__ float dpp_xor1(float x) {   // quad_perm(1,0,3,2)
    return __int_as_float(__builtin_amdgcn_mov_dpp(__float_as_int(x), 0xB1, 0xF, 0xF, true));
}
__device__ __forceinline__ float dpp_xor2(float x) {   // quad_perm(2,3,0,1)
    return __int_as_float(__builtin_amdgcn_mov_dpp(__float_as_int(x), 0x4E, 0xF, 0xF, true));
}
__device__ __forceinline__ float dpp_mir8(float x) {   // ROW_HALF_MIRROR: i<->7-i
    return __int_as_float(__builtin_amdgcn_mov_dpp(__float_as_int(x), 0x141, 0xF, 0xF, true));
}
__device__ __forceinline__ float bperm(int byteaddr, float v) {
    return __int_as_float(__builtin_amdgcn_ds_bpermute(byteaddr, __float_as_int(v)));
}

// One element per WAVE (block=64): no __syncthreads, no in-loop LDS storage.
// y-exchange is pure ds_bpermute (register pulls). W=144 floats/lane; with
// 1-wave blocks + waves_per_eu(1,2) the allocator finally has a 512-VGPR
// budget and no occupancy incentive to evict W (R2-R7: remat/AGPR/scratch).
__global__
__attribute__((amdgpu_flat_work_group_size(64, 64), amdgpu_waves_per_eu(1, 2)))
void horn_kernel(
    const float* __restrict__ input,   // (1024, 784)
    const float* __restrict__ w_ih,    // (94, 1)
    const float* __restrict__ b_ih,    // (94)
    const float* __restrict__ w_hh,    // (94, 94)
    const float* __restrict__ b_hh,    // (94)
    const float* __restrict__ w_ro,    // (10, 94)
    const float* __restrict__ b_ro,    // (10)
    float* __restrict__ out)           // (1024, 10)
{
    __shared__ float xsh[96];          // epilogue x-gather only (one wave/block)

    const int lane = threadIdx.x;      // 0..63
    const int g    = lane >> 3;        // row-group: rows 12g..12g+11
    const int lw   = lane & 7;         // col-chunk: cols 12lw..12lw+11
    const int bb   = blockIdx.x;       // batch element

    const int b0  = lane & 1, b1 = (lane >> 1) & 1, b2v = (lane >> 2) & 1;
    const bool c0 = ((b0 ^ b2v) != 0);
    const bool c1 = ((b1 ^ b2v) != 0);
    const bool c2 = (b2v != 0);

    // ---- W block: rows 12g..12g+11 x cols 12lw..12lw+11, pre-scaled ----
    const int row0 = 12 * g, col0 = 12 * lw;
    f2 w2[12][6];
    #pragma unroll
    for (int i = 0; i < 12; i++) {
        const int rr = row0 + i;
        #pragma unroll
        for (int c = 0; c < 12; c++) {
            const int cc = col0 + c;
            float v = (rr < NUM_NODES && cc < NUM_NODES)
                        ? w_hh[rr * NUM_NODES + cc] * WSCALE : 0.0f;
            w2[i][c >> 1][c & 1] = v;
        }
    }

    // Owned rows after transpose-reduce (R6-verified machinery):
    // nA unique across the 8 lanes; nB (rows 8..11) duplicated on b2-pairs
    // (mir8 partners share c0,c1, so R2+mir8(R2) completes those sums).
    const int nA = row0 + 4 * b2v + 2 * (b1 ^ b2v) + (b0 ^ b2v);
    const int nB = row0 + 8 + 2 * (b1 ^ b2v) + (b0 ^ b2v);
    const float wihA  = (nA < NUM_NODES) ? w_ih[nA] * WSCALE : 0.0f;
    const float biasA = (nA < NUM_NODES) ? (b_ih[nA] + b_hh[nA]) * WSCALE : 0.0f;
    const float wihB  = (nB < NUM_NODES) ? w_ih[nB] * WSCALE : 0.0f;
    const float biasB = (nB < NUM_NODES) ? (b_ih[nB] + b_hh[nB]) * WSCALE : 0.0f;

    // bpermute byte-addresses: node 12*lw+i lives at lane 8*lw + ow[i],
    // in register yA for i<8, yB for i>=8.
    const int owtbl[12] = {0, 1, 2, 3, 7, 6, 5, 4, 0, 1, 2, 3};
    int adr[12];
    #pragma unroll
    for (int i = 0; i < 12; i++) adr[i] = (8 * lw + owtbl[i]) * 4;

    float xA = 0.0f, yA = 0.0f, xB = 0.0f, yB = 0.0f;

    const float* srow = input + (size_t)bb * SEQ_LEN;
    float sc = srow[0];                       // uniform -> s_load

    for (int t = 0; t < SEQ_LEN; t++) {
        const int tn = (t + 1 < SEQ_LEN) ? t + 1 : (SEQ_LEN - 1);
        float sn = srow[tn];                  // prefetch next input scalar

        // ---- pull this lane's 12 y-values (pure register exchange) ----
        float u0 = bperm(adr[0], yA),  u1 = bperm(adr[1], yA);
        float u2 = bperm(adr[2], yA),  u3 = bperm(adr[3], yA);
        float u4 = bperm(adr[4], yA),  u5 = bperm(adr[5], yA);
        float u6 = bperm(adr[6], yA),  u7 = bperm(adr[7], yA);
        float u8 = bperm(adr[8], yB),  u9 = bperm(adr[9], yB);
        float u10 = bperm(adr[10], yB), u11 = bperm(adr[11], yB);
        f2 yy0 = {u0, u1}, yy1 = {u2, u3}, yy2 = {u4, u5};
        f2 yy3 = {u6, u7}, yy4 = {u8, u9}, yy5 = {u10, u11};

        // ---- 12x12 partial dots (144 MACs as packed-f32 FMAs) ----
        f2 P[12];
        #pragma unroll
        for (int i = 0; i < 12; i++) {
            f2 p = w2[i][0] * yy0;
            p += w2[i][1] * yy1;  p += w2[i][2] * yy2;
            p += w2[i][3] * yy3;  p += w2[i][4] * yy4;
            p += w2[i][5] * yy5;
            P[i] = p;
        }
        float P0 = P[0][0] + P[0][1],   P1 = P[1][0] + P[1][1];
        float P2 = P[2][0] + P[2][1],   P3 = P[3][0] + P[3][1];
        float P4 = P[4][0] + P[4][1],   P5 = P[5][0] + P[5][1];
        float P6 = P[6][0] + P[6][1],   P7 = P[7][0] + P[7][1];
        float P8 = P[8][0] + P[8][1],   P9 = P[9][0] + P[9][1];
        float P10 = P[10][0] + P[10][1], P11 = P[11][0] + P[11][1];

        // ---- 8-lane transpose-reduce (R6-verified stages) ----
        float Q0 = (c0 ? P1 : P0) + dpp_xor1(c0 ? P0 : P1);
        float Q1 = (c0 ? P3 : P2) + dpp_xor1(c0 ? P2 : P3);
        float Q2 = (c0 ? P5 : P4) + dpp_xor1(c0 ? P4 : P5);
        float Q3 = (c0 ? P7 : P6) + dpp_xor1(c0 ? P6 : P7);
        float Q4 = (c0 ? P9 : P8) + dpp_xor1(c0 ? P8 : P9);
        float Q5 = (c0 ? P11 : P10) + dpp_xor1(c0 ? P10 : P11);
        float R0 = (c1 ? Q1 : Q0) + dpp_xor2(c1 ? Q0 : Q1);
        float R1 = (c1 ? Q3 : Q2) + dpp_xor2(c1 ? Q2 : Q3);
        float R2 = (c1 ? Q5 : Q4) + dpp_xor2(c1 ? Q4 : Q5);
        float SA = (c2 ? R1 : R0) + dpp_mir8(c2 ? R0 : R1);  // full dot, row nA
        float SB = R2 + dpp_mir8(R2);                        // full dot, row nB

        // ---- dynamics for both owned rows ----
        float eA = __builtin_amdgcn_exp2f(fmaf(sc, wihA, biasA) + SA);
        float aA = 0.5f - __builtin_amdgcn_rcpf(eA + 1.0f);  // 0.5*tanh(A)
        aA = fmaf(-TWO_GAMMA, yA, aA);
        aA = fmaf(-OM2, xA, aA);
        xA += yA;  yA += aA;

        float eB = __builtin_amdgcn_exp2f(fmaf(sc, wihB, biasB) + SB);
        float aB = 0.5f - __builtin_amdgcn_rcpf(eB + 1.0f);
        aB = fmaf(-TWO_GAMMA, yB, aB);
        aB = fmaf(-OM2, xB, aB);
        xB += yB;  yB += aB;

        sc = sn;
    }

    // ---- epilogue: gather x, project to classes (same-wave, no barrier) ----
    xsh[nA] = xA;
    xsh[nB] = xB;      // b2-pair writes same value to same slot: benign
    asm volatile("s_waitcnt lgkmcnt(0)" ::: "memory");

    if (lane < OUT_CLASSES) {
        float acc = b_ro[lane];
        #pragma unroll 2
        for (int j = 0; j < NUM_NODES; j++) {
            acc += xsh[j] * w_ro[lane * NUM_NODES + j];
        }
        out[(size_t)bb * OUT_CLASSES + lane] = acc;
    }
}

extern "C" void kernel_launch(void* const* d_in, const int* in_sizes, int n_in,
                              void* d_out, int out_size, void* d_ws, size_t ws_size,
                              hipStream_t stream) {
    const float* input = (const float*)d_in[0];
    const float* w_ih  = (const float*)d_in[1];
    const float* b_ih  = (const float*)d_in[2];
    const float* w_hh  = (const float*)d_in[3];
    const float* b_hh  = (const float*)d_in[4];
    const float* w_ro  = (const float*)d_in[5];
    const float* b_ro  = (const float*)d_in[6];
    float* out = (float*)d_out;

    const int batch = in_sizes[0] / SEQ_LEN;   // 1024
    dim3 grid(batch);                          // 1 element per 1-wave block
    dim3 block(64);

    hipLaunchKernelGGL(horn_kernel, grid, block, 0, stream,
                       input, w_ih, b_ih, w_hh, b_hh, w_ro, b_ro, out);
}

// Round 9
// 357.952 us; speedup vs baseline: 1.3067x; 1.0577x over previous
//
#include <hip/hip_runtime.h>
#include <math.h>

#define NUM_NODES 94
#define SEQ_LEN 784
#define OUT_CLASSES 10

#define TWO_GAMMA 0.2f
#define OM2 0.0503551324598949f            // (2*pi/28)^2
#define INV_SQRT_N 0.103142124625879       // 1/sqrt(94)
#define LOG2E 1.4426950408889634
// exp2 arg = 2A*log2e -> fold 2*INV_SQRT_N*LOG2E into all I-path weights
#define WSCALE ((float)(2.0 * INV_SQRT_N * LOG2E))

typedef float f2 __attribute__((ext_vector_type(2)));
typedef float f4 __attribute__((ext_vector_type(4)));

__device__ __forceinline__ float dpp_xor1(float x) {   // quad_perm(1,0,3,2)
    return __int_as_float(__builtin_amdgcn_mov_dpp(__float_as_int(x), 0xB1, 0xF, 0xF, true));
}
__device__ __forceinline__ float dpp_xor2(float x) {   // quad_perm(2,3,0,1)
    return __int_as_float(__builtin_amdgcn_mov_dpp(__float_as_int(x), 0x4E, 0xF, 0xF, true));
}
__device__ __forceinline__ float dpp_mir8(float x) {   // ROW_HALF_MIRROR: i<->7-i
    return __int_as_float(__builtin_amdgcn_mov_dpp(__float_as_int(x), 0x141, 0xF, 0xF, true));
}

// One element per WAVE (block=64): no __syncthreads. y-exchange is a
// same-wave LDS transpose: 2 ds_write_b32 + 3 ds_read_b128 (vs R8's 12
// ds_bpermute @ ~2 conflict-cyc each). waves_per_eu(1,1): we can never
// exceed 1 wave/EU anyway (1024 single-wave blocks = 4/CU), and telling
// the allocator unlocks the full 512-VGPR budget so W (144 floats) stays
// in arch VGPRs (R8: VGPR=100 -> AGPR copies + scratch, FETCH +1.5MB).
__global__
__attribute__((amdgpu_flat_work_group_size(64, 64), amdgpu_waves_per_eu(1, 1)))
void horn_kernel(
    const float* __restrict__ input,   // (1024, 784)
    const float* __restrict__ w_ih,    // (94, 1)
    const float* __restrict__ b_ih,    // (94)
    const float* __restrict__ w_hh,    // (94, 94)
    const float* __restrict__ b_hh,    // (94)
    const float* __restrict__ w_ro,    // (10, 94)
    const float* __restrict__ b_ro,    // (10)
    float* __restrict__ out)           // (1024, 10)
{
    __shared__ __align__(16) float ysh[96];   // y exchange + epilogue x-gather

    const int lane = threadIdx.x;      // 0..63
    const int g    = lane >> 3;        // row-group: rows 12g..12g+11
    const int lw   = lane & 7;         // col-chunk: cols 12lw..12lw+11
    const int bb   = blockIdx.x;       // batch element

    const int b0  = lane & 1, b1 = (lane >> 1) & 1, b2v = (lane >> 2) & 1;
    const bool c0 = ((b0 ^ b2v) != 0);
    const bool c1 = ((b1 ^ b2v) != 0);
    const bool c2 = (b2v != 0);

    // ---- W block: rows 12g..12g+11 x cols 12lw..12lw+11, pre-scaled ----
    const int row0 = 12 * g, col0 = 12 * lw;
    f2 w2[12][6];
    #pragma unroll
    for (int i = 0; i < 12; i++) {
        const int rr = row0 + i;
        #pragma unroll
        for (int c = 0; c < 12; c++) {
            const int cc = col0 + c;
            float v = (rr < NUM_NODES && cc < NUM_NODES)
                        ? w_hh[rr * NUM_NODES + cc] * WSCALE : 0.0f;
            w2[i][c >> 1][c & 1] = v;
        }
    }

    // Owned rows after transpose-reduce (verified R6-R8):
    // nA unique across the 8 lanes of a group; nB (rows 8..11) duplicated on
    // b2-pairs (mir8 partners share c0,c1 -> R2+mir8(R2) completes the sum).
    const int nA = row0 + 4 * b2v + 2 * (b1 ^ b2v) + (b0 ^ b2v);
    const int nB = row0 + 8 + 2 * (b1 ^ b2v) + (b0 ^ b2v);
    const float wihA  = (nA < NUM_NODES) ? w_ih[nA] * WSCALE : 0.0f;
    const float biasA = (nA < NUM_NODES) ? (b_ih[nA] + b_hh[nA]) * WSCALE : 0.0f;
    const float wihB  = (nB < NUM_NODES) ? w_ih[nB] * WSCALE : 0.0f;
    const float biasB = (nB < NUM_NODES) ? (b_ih[nB] + b_hh[nB]) * WSCALE : 0.0f;

    float xA = 0.0f, yA = 0.0f, xB = 0.0f, yB = 0.0f;

    const float* srow = input + (size_t)bb * SEQ_LEN;
    float sc = srow[0];                       // uniform -> scalar load

    const f4* yv = (const f4*)&ysh[col0];     // 48B*lw: 16B-aligned

    for (int t = 0; t < SEQ_LEN; t++) {
        const int tn = (t + 1 < SEQ_LEN) ? t + 1 : (SEQ_LEN - 1);
        float sn = srow[tn];                  // prefetch next input scalar

        // ---- same-wave LDS transpose: publish own y, read needed chunk ----
        // Writes: nA unique (64 slots), nB pair-duplicated same value: benign.
        // Wave-lockstep => next iteration's writes cannot pass these reads.
        ysh[nA] = yA;
        ysh[nB] = yB;
        asm volatile("s_waitcnt lgkmcnt(0)" ::: "memory");
        f4 Y0 = yv[0], Y1 = yv[1], Y2 = yv[2];   // 8-way broadcast, all banks
        f2 yy0 = __builtin_shufflevector(Y0, Y0, 0, 1);
        f2 yy1 = __builtin_shufflevector(Y0, Y0, 2, 3);
        f2 yy2 = __builtin_shufflevector(Y1, Y1, 0, 1);
        f2 yy3 = __builtin_shufflevector(Y1, Y1, 2, 3);
        f2 yy4 = __builtin_shufflevector(Y2, Y2, 0, 1);
        f2 yy5 = __builtin_shufflevector(Y2, Y2, 2, 3);

        // ---- 12x12 partial dots (144 MACs as packed-f32 FMAs) ----
        f2 P[12];
        #pragma unroll
        for (int i = 0; i < 12; i++) {
            f2 p = w2[i][0] * yy0;
            p += w2[i][1] * yy1;  p += w2[i][2] * yy2;
            p += w2[i][3] * yy3;  p += w2[i][4] * yy4;
            p += w2[i][5] * yy5;
            P[i] = p;
        }
        float P0 = P[0][0] + P[0][1],   P1 = P[1][0] + P[1][1];
        float P2 = P[2][0] + P[2][1],   P3 = P[3][0] + P[3][1];
        float P4 = P[4][0] + P[4][1],   P5 = P[5][0] + P[5][1];
        float P6 = P[6][0] + P[6][1],   P7 = P[7][0] + P[7][1];
        float P8 = P[8][0] + P[8][1],   P9 = P[9][0] + P[9][1];
        float P10 = P[10][0] + P[10][1], P11 = P[11][0] + P[11][1];

        // ---- 8-lane transpose-reduce (verified stages) ----
        float Q0 = (c0 ? P1 : P0) + dpp_xor1(c0 ? P0 : P1);
        float Q1 = (c0 ? P3 : P2) + dpp_xor1(c0 ? P2 : P3);
        float Q2 = (c0 ? P5 : P4) + dpp_xor1(c0 ? P4 : P5);
        float Q3 = (c0 ? P7 : P6) + dpp_xor1(c0 ? P6 : P7);
        float Q4 = (c0 ? P9 : P8) + dpp_xor1(c0 ? P8 : P9);
        float Q5 = (c0 ? P11 : P10) + dpp_xor1(c0 ? P10 : P11);
        float R0 = (c1 ? Q1 : Q0) + dpp_xor2(c1 ? Q0 : Q1);
        float R1 = (c1 ? Q3 : Q2) + dpp_xor2(c1 ? Q2 : Q3);
        float R2 = (c1 ? Q5 : Q4) + dpp_xor2(c1 ? Q4 : Q5);
        float SA = (c2 ? R1 : R0) + dpp_mir8(c2 ? R0 : R1);  // row nA full dot
        float SB = R2 + dpp_mir8(R2);                        // row nB full dot

        // ---- dynamics for both owned rows (independent chains) ----
        float eA = __builtin_amdgcn_exp2f(fmaf(sc, wihA, biasA) + SA);
        float aA = 0.5f - __builtin_amdgcn_rcpf(eA + 1.0f);  // 0.5*tanh(A)
        aA = fmaf(-TWO_GAMMA, yA, aA);
        aA = fmaf(-OM2, xA, aA);
        xA += yA;  yA += aA;

        float eB = __builtin_amdgcn_exp2f(fmaf(sc, wihB, biasB) + SB);
        float aB = 0.5f - __builtin_amdgcn_rcpf(eB + 1.0f);
        aB = fmaf(-TWO_GAMMA, yB, aB);
        aB = fmaf(-OM2, xB, aB);
        xB += yB;  yB += aB;

        sc = sn;
    }

    // ---- epilogue: gather x, project to classes (same-wave, no barrier) ----
    ysh[nA] = xA;
    ysh[nB] = xB;      // pair writes same value: benign
    asm volatile("s_waitcnt lgkmcnt(0)" ::: "memory");

    if (lane < OUT_CLASSES) {
        float acc = b_ro[lane];
        #pragma unroll 2
        for (int j = 0; j < NUM_NODES; j++) {
            acc += ysh[j] * w_ro[lane * NUM_NODES + j];
        }
        out[(size_t)bb * OUT_CLASSES + lane] = acc;
    }
}

extern "C" void kernel_launch(void* const* d_in, const int* in_sizes, int n_in,
                              void* d_out, int out_size, void* d_ws, size_t ws_size,
                              hipStream_t stream) {
    const float* input = (const float*)d_in[0];
    const float* w_ih  = (const float*)d_in[1];
    const float* b_ih  = (const float*)d_in[2];
    const float* w_hh  = (const float*)d_in[3];
    const float* b_hh  = (const float*)d_in[4];
    const float* w_ro  = (const float*)d_in[5];
    const float* b_ro  = (const float*)d_in[6];
    float* out = (float*)d_out;

    const int batch = in_sizes[0] / SEQ_LEN;   // 1024
    dim3 grid(batch);                          // 1 element per 1-wave block
    dim3 block(64);

    hipLaunchKernelGGL(horn_kernel, grid, block, 0, stream,
                       input, w_ih, b_ih, w_hh, b_hh, w_ro, b_ro, out);
}